// Round 3
// baseline (456.255 us; speedup 1.0000x reference)
//
#include <hip/hip_runtime.h>
#include <math.h>

#define N_NODES 100000
#define N_EDGES 400000
#define HID 128
#define HEADS 4
#define OUT_C 64
#define HD 256   // HEADS*OUT_C
#define SCAN_CHUNK 1024
#define NB_SCAN ((N_NODES + SCAN_CHUNK - 1) / SCAN_CHUNK)   // 98

typedef __attribute__((ext_vector_type(8))) short bf16x8;   // 8 bf16 = 4 VGPRs
typedef __attribute__((ext_vector_type(4))) float f32x4;

// fp32 -> bf16 round-to-nearest-even
__device__ __forceinline__ unsigned short fbf(float f) {
    unsigned u = __float_as_uint(f);
    unsigned r = (u + 0x7fffu + ((u >> 16) & 1u)) >> 16;
    return (unsigned short)r;
}
__device__ __forceinline__ float bf2f(unsigned short u) {
    return __uint_as_float(((unsigned)u) << 16);
}

// async global->LDS, 16B per lane; LDS dest = wave-uniform base + lane*16
__device__ __forceinline__ void gl_lds16(const void* g, void* l) {
    __builtin_amdgcn_global_load_lds(
        (const __attribute__((address_space(1))) unsigned int*)g,
        (__attribute__((address_space(3))) unsigned int*)l,
        16, 0, 0);
}

// ---------- K0: zero deg + cursor ----------
__global__ __launch_bounds__(256) void init_zero(int* __restrict__ deg,
                                                 int* __restrict__ cursor) {
    int i = blockIdx.x * 256 + threadIdx.x;
    if (i < N_NODES) { deg[i] = 0; cursor[i] = 0; }
}

// ---------- CSR build: degree count ----------
__global__ __launch_bounds__(256) void k_deg(const int* __restrict__ ei,
                                             int* __restrict__ deg) {
    int e = blockIdx.x * 256 + threadIdx.x;
    if (e < N_EDGES) atomicAdd(&deg[ei[N_EDGES + e]], 1);
}

// ---------- scan 1 ----------
__global__ __launch_bounds__(256) void k_scan1(const int* __restrict__ deg,
                                               int* __restrict__ rp,
                                               int* __restrict__ bsum) {
    __shared__ int ts[256];
    int b = blockIdx.x, t = threadIdx.x;
    int base = b * SCAN_CHUNK + t * 4;
    int vv[4];
    int s = 0;
#pragma unroll
    for (int i = 0; i < 4; ++i) {
        int d = (base + i < N_NODES) ? deg[base + i] : 0;
        vv[i] = s;
        s += d;
    }
    ts[t] = s;
    __syncthreads();
    for (int off = 1; off < 256; off <<= 1) {
        int x = (t >= off) ? ts[t - off] : 0;
        __syncthreads();
        ts[t] += x;
        __syncthreads();
    }
    int ex = ts[t] - s;
#pragma unroll
    for (int i = 0; i < 4; ++i)
        if (base + i < N_NODES) rp[base + i] = ex + vv[i];
    if (t == 255) bsum[b] = ts[255];
}

// ---------- scan 2 ----------
__global__ __launch_bounds__(256) void k_scan2(int* __restrict__ bsum) {
    __shared__ int ts[256];
    int t = threadIdx.x;
    int v = (t < NB_SCAN) ? bsum[t] : 0;
    ts[t] = v;
    __syncthreads();
    for (int off = 1; off < 256; off <<= 1) {
        int x = (t >= off) ? ts[t - off] : 0;
        __syncthreads();
        ts[t] += x;
        __syncthreads();
    }
    if (t < NB_SCAN) bsum[t] = ts[t] - v;
}

// ---------- bucket: fill csr_src / csr_dst / csr_eid (rp finalized inline via bsum) ----------
__global__ __launch_bounds__(256) void k_bucket(const int* __restrict__ ei,
                                                const int* __restrict__ rp,
                                                const int* __restrict__ bsum,
                                                int* __restrict__ cursor,
                                                int* __restrict__ csr_src,
                                                int* __restrict__ csr_dst,
                                                int* __restrict__ csr_eid) {
    int e = blockIdx.x * 256 + threadIdx.x;
    if (e >= N_EDGES) return;
    int src = ei[e];
    int d   = ei[N_EDGES + e];
    int idx = atomicAdd(&cursor[d], 1);
    int s   = rp[d] + bsum[d >> 10] + idx;
    csr_src[s] = src;
    csr_dst[s] = d;
    csr_eid[s] = e;
}

// ---------- merged weight packing ----------
// i in [0,16384):      4 projection weights [128,256] -> [z][kt][nt][lane][8]
// i in [16384,24576):  fused PD weight Wc[256k][256n] -> [kt(8)][nt(16)][lane][8]
// i in [24576,25600):  W2 [128,64] -> [kt][nt][lane][8]
__global__ __launch_bounds__(256) void pack_all(
    const float* __restrict__ Wq, const float* __restrict__ Wk,
    const float* __restrict__ Wv, const float* __restrict__ Ws,
    const float* __restrict__ W1, const float* __restrict__ W2,
    unsigned short* __restrict__ Wp, unsigned short* __restrict__ Wcp,
    unsigned short* __restrict__ W2p) {
    int i = blockIdx.x * 256 + threadIdx.x;   // 25600 total
    int lane = i & 63;
    int q = lane >> 4, c = lane & 15;
    if (i < 16384) {
        int nt = (i >> 6) & 15, kt = (i >> 10) & 3, z = i >> 12;
        const float* W = (z == 0) ? Wq : (z == 1) ? Wk : (z == 2) ? Wv : Ws;
#pragma unroll
        for (int j = 0; j < 8; ++j)
            Wp[i * 8 + j] = fbf(W[(kt * 32 + q * 8 + j) * HD + nt * 16 + c]);
    } else if (i < 24576) {
        int ii = i - 16384;
        int nt = (ii >> 6) & 15, kt = ii >> 10;
        int n = nt * 16 + c;
#pragma unroll
        for (int j = 0; j < 8; ++j) {
            int k = kt * 32 + q * 8 + j;
            float v = (n < 128) ? W1[k * 128 + n] : W1[(k + 256) * 128 + (n - 128)];
            Wcp[ii * 8 + j] = fbf(v);
        }
    } else if (i < 25600) {
        int ii = i - 24576;
        int nt = (ii >> 6) & 3, kt = ii >> 8;
#pragma unroll
        for (int j = 0; j < 8; ++j)
            W2p[ii * 8 + j] = fbf(W2[(kt * 32 + q * 8 + j) * 64 + nt * 16 + c]);
    }
}

// ---------- K_pre: H = bf16(x + mem), one streaming pass ----------
__global__ __launch_bounds__(256) void k_pre(const float* __restrict__ x,
                                             const float* __restrict__ mem,
                                             unsigned short* __restrict__ H) {
    int idx = blockIdx.x * 256 + threadIdx.x;      // chunk of 8 elems
    if (idx >= N_NODES * HID / 8) return;          // 1,600,000 chunks
    const float4* x4 = (const float4*)x;
    const float4* m4 = (const float4*)mem;
    float4 a0 = x4[(size_t)idx * 2],     a1 = x4[(size_t)idx * 2 + 1];
    float4 b0 = m4[(size_t)idx * 2],     b1 = m4[(size_t)idx * 2 + 1];
    bf16x8 hv;
    hv[0] = (short)fbf(a0.x + b0.x); hv[1] = (short)fbf(a0.y + b0.y);
    hv[2] = (short)fbf(a0.z + b0.z); hv[3] = (short)fbf(a0.w + b0.w);
    hv[4] = (short)fbf(a1.x + b1.x); hv[5] = (short)fbf(a1.y + b1.y);
    hv[6] = (short)fbf(a1.z + b1.z); hv[7] = (short)fbf(a1.w + b1.w);
    *(bf16x8*)&H[(size_t)idx * 8] = hv;
}

// ---------- K1: projection GEMM, z split across gridDim.y ----------
// z=0 -> Q [N,256]
// z=1 -> K into KV lane-interleaved: col c -> KV[n*512 + (c>>2)*8 + (c&3)]
// z=2 -> V into KV lane-interleaved: col c -> KV[n*512 + (c>>2)*8 + 4 + (c&3)]
// z=3 -> S [N,256]
// (lane l of k_attn then reads its 16 B [k0..k3 v0..v3] with ONE dwordx4)
__global__ __launch_bounds__(256, 4) void gemm4(
    const unsigned short* __restrict__ H,
    const unsigned short* __restrict__ Wp,
    const float* __restrict__ bq, const float* __restrict__ bk,
    const float* __restrict__ bv, const float* __restrict__ bs,
    unsigned short* __restrict__ Q, unsigned short* __restrict__ KV,
    unsigned short* __restrict__ S)
{
    __shared__ __align__(16) short sh[4 * 64 * 68];   // 34816 B union:
    short* As = sh;                                    //   As [64][128] swizzled (16 KB)
                                                       //   slab 4 x [64][68] after barrier

    const int t = threadIdx.x;
    const int w = t >> 6, l = t & 63;
    const int q = l >> 4, c = l & 15;
    const int z  = blockIdx.y;
    const int m0 = blockIdx.x * 64;

    // --- async stage H tile 64x128 bf16 (16 KB): wave w owns rows [w*16, w*16+16)
    // linear LDS dest, XOR-swizzled GLOBAL source: LDS row r, 16B-slot s holds
    // H chunk (s ^ (r&7)) so ds_read_b128 below sits at the 8-way b128 floor.
#pragma unroll
    for (int i = 0; i < 4; ++i) {
        int rbase = w * 16 + i * 4;          // 4 rows = 1 KB per wave-instr
        int r  = rbase + (l >> 4);
        int gr = m0 + r; if (gr >= N_NODES) gr = N_NODES - 1;   // clamp: tail rows garbage, stores guarded
        int ks = (l & 15) ^ (r & 7);
        gl_lds16(&H[(size_t)gr * HID + ks * 8], &As[rbase * 128]);
    }

    // per-z output meta + bias (issued before the barrier)
    const float* bz = (z == 0) ? bq : (z == 1) ? bk : (z == 2) ? bv : bs;
    float bb[4];
#pragma unroll
    for (int nt = 0; nt < 4; ++nt) bb[nt] = bz[w * 64 + nt * 16 + c];

    f32x4 acc[4][4];
#pragma unroll
    for (int mt = 0; mt < 4; ++mt)
#pragma unroll
        for (int nt = 0; nt < 4; ++nt) acc[mt][nt] = (f32x4){0.f, 0.f, 0.f, 0.f};

    __syncthreads();

#pragma unroll
    for (int kt = 0; kt < 4; ++kt) {
        bf16x8 af[4];
#pragma unroll
        for (int mt = 0; mt < 4; ++mt) {
            int row  = mt * 16 + c;
            int slot = (kt * 4 + q) ^ (row & 7);
            af[mt] = *(const bf16x8*)&As[row * 128 + slot * 8];
        }
#pragma unroll
        for (int nt = 0; nt < 4; ++nt) {
            bf16x8 bw8 = *(const bf16x8*)&Wp[(size_t)(((z * 4 + kt) * 16 + w * 4 + nt) * 64 + l) * 8];
#pragma unroll
            for (int mt = 0; mt < 4; ++mt)
                acc[mt][nt] = __builtin_amdgcn_mfma_f32_16x16x32_bf16(af[mt], bw8, acc[mt][nt], 0, 0, 0);
        }
    }
    __syncthreads();   // all As reads done; slab aliases As

    short* slab = &sh[w * 64 * 68];
#pragma unroll
    for (int nt = 0; nt < 4; ++nt)
#pragma unroll
        for (int mt = 0; mt < 4; ++mt)
#pragma unroll
            for (int r = 0; r < 4; ++r)
                slab[(mt * 16 + q * 4 + r) * 68 + nt * 16 + c] =
                    (short)fbf(acc[mt][nt][r] + bb[nt]);

    const int srow = l >> 3, schk = l & 7;
    if (z == 1 || z == 2) {
        // lane-interleaved KV store: slab cols [w*64 + schk*8 .. +8) map to
        // KV[n*512 + w*128 + schk*16 + voff + {0..3, 8..11}]
        const int voff = (z == 2) ? 4 : 0;
#pragma unroll
        for (int j = 0; j < 8; ++j) {
            int row = j * 8 + srow;
            int gr  = m0 + row;
            if (gr < N_NODES) {
                const short* sp = &slab[row * 68 + schk * 8];
                size_t base = (size_t)gr * 512 + w * 128 + schk * 16 + voff;
                *(ushort4*)&KV[base]     = *(const ushort4*)sp;
                *(ushort4*)&KV[base + 8] = *(const ushort4*)(sp + 4);
            }
        }
    } else {
        unsigned short* Oz = (z == 0) ? Q : S;
#pragma unroll
        for (int j = 0; j < 8; ++j) {
            int row = j * 8 + srow;
            int gr  = m0 + row;
            if (gr < N_NODES)
                *(bf16x8*)&Oz[(size_t)gr * HD + w * 64 + schk * 8] =
                    *(const bf16x8*)&slab[row * 68 + schk * 8];
        }
    }
}

// ---------- K2: fused attention, one wave per node ----------
// KV lane-interleaved: lane l reads ONE 16 B chunk = [K[l*4..+4) | V[l*4..+4)]
// No-max softmax (scores tiny, shift-invariant); 4-edge unroll for MLP.
__global__ __launch_bounds__(256) void k_attn(
    const int* __restrict__ rp, const int* __restrict__ bsum,
    const int* __restrict__ deg, const int* __restrict__ csr_src,
    const unsigned short* __restrict__ Q, const unsigned short* __restrict__ KV,
    const unsigned short* __restrict__ S,
    unsigned short* __restrict__ out)
{
    int node = blockIdx.x * 4 + (threadIdx.x >> 6);
    int l = threadIdx.x & 63;
    if (node >= N_NODES) return;
    int start = rp[node] + bsum[node >> 10];
    int cnt   = deg[node];

    float q0, q1, q2, q3;   // pre-scaled by 1/sqrt(64) = 0.125 (exact pow2)
    {
        ushort4 u = *(const ushort4*)&Q[(size_t)node * HD + l * 4];
        q0 = bf2f(u.x) * 0.125f; q1 = bf2f(u.y) * 0.125f;
        q2 = bf2f(u.z) * 0.125f; q3 = bf2f(u.w) * 0.125f;
    }

    float d = 0.f;
    float a0 = 0.f, a1 = 0.f, a2 = 0.f, a3 = 0.f;

    int i = 0;
    for (; i + 4 <= cnt; i += 4) {
        int s0 = csr_src[start + i];
        int s1 = csr_src[start + i + 1];
        int s2 = csr_src[start + i + 2];
        int s3 = csr_src[start + i + 3];
        bf16x8 k0 = *(const bf16x8*)&KV[(size_t)s0 * 512 + l * 8];
        bf16x8 k1 = *(const bf16x8*)&KV[(size_t)s1 * 512 + l * 8];
        bf16x8 k2 = *(const bf16x8*)&KV[(size_t)s2 * 512 + l * 8];
        bf16x8 k3 = *(const bf16x8*)&KV[(size_t)s3 * 512 + l * 8];
        float sA = q0 * bf2f((unsigned short)k0[0]) + q1 * bf2f((unsigned short)k0[1])
                 + q2 * bf2f((unsigned short)k0[2]) + q3 * bf2f((unsigned short)k0[3]);
        float sB = q0 * bf2f((unsigned short)k1[0]) + q1 * bf2f((unsigned short)k1[1])
                 + q2 * bf2f((unsigned short)k1[2]) + q3 * bf2f((unsigned short)k1[3]);
        float sC = q0 * bf2f((unsigned short)k2[0]) + q1 * bf2f((unsigned short)k2[1])
                 + q2 * bf2f((unsigned short)k2[2]) + q3 * bf2f((unsigned short)k2[3]);
        float sD = q0 * bf2f((unsigned short)k3[0]) + q1 * bf2f((unsigned short)k3[1])
                 + q2 * bf2f((unsigned short)k3[2]) + q3 * bf2f((unsigned short)k3[3]);
        sA += __shfl_xor(sA, 1); sB += __shfl_xor(sB, 1);
        sC += __shfl_xor(sC, 1); sD += __shfl_xor(sD, 1);
        sA += __shfl_xor(sA, 2); sB += __shfl_xor(sB, 2);
        sC += __shfl_xor(sC, 2); sD += __shfl_xor(sD, 2);
        sA += __shfl_xor(sA, 4); sB += __shfl_xor(sB, 4);
        sC += __shfl_xor(sC, 4); sD += __shfl_xor(sD, 4);
        sA += __shfl_xor(sA, 8); sB += __shfl_xor(sB, 8);
        sC += __shfl_xor(sC, 8); sD += __shfl_xor(sD, 8);
        float eA = __expf(sA), eB = __expf(sB), eC = __expf(sC), eD = __expf(sD);
        d += (eA + eB) + (eC + eD);
        a0 += eA * bf2f((unsigned short)k0[4]) + eB * bf2f((unsigned short)k1[4])
            + eC * bf2f((unsigned short)k2[4]) + eD * bf2f((unsigned short)k3[4]);
        a1 += eA * bf2f((unsigned short)k0[5]) + eB * bf2f((unsigned short)k1[5])
            + eC * bf2f((unsigned short)k2[5]) + eD * bf2f((unsigned short)k3[5]);
        a2 += eA * bf2f((unsigned short)k0[6]) + eB * bf2f((unsigned short)k1[6])
            + eC * bf2f((unsigned short)k2[6]) + eD * bf2f((unsigned short)k3[6]);
        a3 += eA * bf2f((unsigned short)k0[7]) + eB * bf2f((unsigned short)k1[7])
            + eC * bf2f((unsigned short)k2[7]) + eD * bf2f((unsigned short)k3[7]);
    }
    for (; i < cnt; ++i) {
        int s0 = csr_src[start + i];
        bf16x8 k0 = *(const bf16x8*)&KV[(size_t)s0 * 512 + l * 8];
        float sA = q0 * bf2f((unsigned short)k0[0]) + q1 * bf2f((unsigned short)k0[1])
                 + q2 * bf2f((unsigned short)k0[2]) + q3 * bf2f((unsigned short)k0[3]);
        sA += __shfl_xor(sA, 1);
        sA += __shfl_xor(sA, 2);
        sA += __shfl_xor(sA, 4);
        sA += __shfl_xor(sA, 8);
        float eA = __expf(sA);
        d += eA;
        a0 += eA * bf2f((unsigned short)k0[4]);
        a1 += eA * bf2f((unsigned short)k0[5]);
        a2 += eA * bf2f((unsigned short)k0[6]);
        a3 += eA * bf2f((unsigned short)k0[7]);
    }

    float inv = 1.f / (d + 1e-16f);
    ushort4 su = *(const ushort4*)&S[(size_t)node * HD + l * 4];
    ushort4 ov = make_ushort4(fbf(bf2f(su.x) + a0 * inv),
                              fbf(bf2f(su.y) + a1 * inv),
                              fbf(bf2f(su.z) + a2 * inv),
                              fbf(bf2f(su.w) + a3 * inv));
    *(ushort4*)&out[(size_t)node * HD + l * 4] = ov;
}

// ---------- K3: PD GEMM — PD[n] = out[n] @ [W1_top | W1_bot],  M=100k K=256 N=256 ----------
// async global_load_lds staging (linear LDS, XOR-pre-swizzled global source)
__global__ __launch_bounds__(256, 4) void pd_gemm(
    const unsigned short* __restrict__ outb,
    const unsigned short* __restrict__ Wcp,
    unsigned short* __restrict__ PD)
{
    __shared__ __align__(16) short sh[4 * 64 * 68];   // 34816 B union:
    short* As = sh;                                    //   As [64][256] swizzled (32 KB)
                                                       //   slab 4 x [64][68] after barrier

    const int t = threadIdx.x;
    const int w = t >> 6, l = t & 63;
    const int q = l >> 4, c = l & 15;
    const int m0 = blockIdx.x * 64;

    // async stage A = out[m0..m0+64, 0..256) bf16: wave w stages rows [w*16, w*16+16)
    // 2 rows (1 KB) per gl_lds16; LDS slot j of row r holds global chunk j ^ (r&7)
#pragma unroll
    for (int i = 0; i < 8; ++i) {
        int rbase = w * 16 + i * 2;
        int r  = rbase + (l >> 5);
        int gr = m0 + r; if (gr >= N_NODES) gr = N_NODES - 1;   // clamp; stores guarded
        int s  = (l & 31) ^ (r & 7);
        gl_lds16(&outb[(size_t)gr * HD + s * 8], &As[rbase * 256]);
    }

    f32x4 acc[4][4];
#pragma unroll
    for (int mt = 0; mt < 4; ++mt)
#pragma unroll
        for (int nt = 0; nt < 4; ++nt) acc[mt][nt] = (f32x4){0.f, 0.f, 0.f, 0.f};

    __syncthreads();

#pragma unroll
    for (int kt = 0; kt < 8; ++kt) {
        bf16x8 af[4];
#pragma unroll
        for (int mt = 0; mt < 4; ++mt) {
            int row  = mt * 16 + c;
            int slot = (kt * 4 + q) ^ (row & 7);
            af[mt] = *(const bf16x8*)&As[row * 256 + slot * 8];
        }
#pragma unroll
        for (int nt = 0; nt < 4; ++nt) {
            int ntg = w * 4 + nt;
            bf16x8 bv8 = *(const bf16x8*)&Wcp[(size_t)((kt * 16 + ntg) * 64 + l) * 8];
#pragma unroll
            for (int mt = 0; mt < 4; ++mt)
                acc[mt][nt] = __builtin_amdgcn_mfma_f32_16x16x32_bf16(af[mt], bv8, acc[mt][nt], 0, 0, 0);
        }
    }
    __syncthreads();   // all As reads done; slab aliases As

    short* slab = &sh[w * 64 * 68];
#pragma unroll
    for (int nt = 0; nt < 4; ++nt)
#pragma unroll
        for (int mt = 0; mt < 4; ++mt)
#pragma unroll
            for (int r = 0; r < 4; ++r)
                slab[(mt * 16 + q * 4 + r) * 68 + nt * 16 + c] =
                    (short)fbf(acc[mt][nt][r]);
    const int srow = l >> 3, schk = l & 7;
#pragma unroll
    for (int j = 0; j < 8; ++j) {
        int row = j * 8 + srow;
        int gr = m0 + row;
        if (gr < N_NODES)
            *(bf16x8*)&PD[(size_t)gr * HD + w * 64 + schk * 8] =
                *(const bf16x8*)&slab[row * 68 + schk * 8];
    }
}

// ---------- K5: light edge MLP — h1 = relu(P[src]+D[dst]+b1); layer2 MFMA; layer3 ----------
__global__ __launch_bounds__(256) void edge_mlp_pd(
    const int* __restrict__ csr_src, const int* __restrict__ csr_dst,
    const int* __restrict__ csr_eid,
    const unsigned short* __restrict__ PD,
    const float* __restrict__ b1,
    const unsigned short* __restrict__ W2p, const float* __restrict__ b2,
    const float* __restrict__ W3, const float* __restrict__ b3,
    float* __restrict__ rating)
{
    __shared__ __align__(16) char lds[64 * 136 * 2];   // 17408 B union:
    short* h1t = (short*)lds;                          //   h1 bf16 [64][136]
    float* h2s = (float*)lds;                          //   h2 f32 [64][65] (aliases after barrier)

    const int t = threadIdx.x;
    const int w = t >> 6, l = t & 63;
    const int q = l >> 4, c = l & 15;
    const int e0 = blockIdx.x * 64;

    // stage h1 = relu(P[src] + D[dst] + b1): 64 rows x 128 cols bf16
#pragma unroll
    for (int j = 0; j < 4; ++j) {
        int idx = t + j * 256;          // 1024 chunks of 8 elems
        int row = idx >> 4, ch = idx & 15;
        int src = csr_src[e0 + row];
        int dst = csr_dst[e0 + row];
        bf16x8 pv = *(const bf16x8*)&PD[(size_t)src * HD + ch * 8];
        bf16x8 dv = *(const bf16x8*)&PD[(size_t)dst * HD + 128 + ch * 8];
        float4 ba = *(const float4*)&b1[ch * 8];
        float4 bb = *(const float4*)&b1[ch * 8 + 4];
        bf16x8 hv;
        hv[0] = (short)fbf(fmaxf(bf2f((unsigned short)pv[0]) + bf2f((unsigned short)dv[0]) + ba.x, 0.f));
        hv[1] = (short)fbf(fmaxf(bf2f((unsigned short)pv[1]) + bf2f((unsigned short)dv[1]) + ba.y, 0.f));
        hv[2] = (short)fbf(fmaxf(bf2f((unsigned short)pv[2]) + bf2f((unsigned short)dv[2]) + ba.z, 0.f));
        hv[3] = (short)fbf(fmaxf(bf2f((unsigned short)pv[3]) + bf2f((unsigned short)dv[3]) + ba.w, 0.f));
        hv[4] = (short)fbf(fmaxf(bf2f((unsigned short)pv[4]) + bf2f((unsigned short)dv[4]) + bb.x, 0.f));
        hv[5] = (short)fbf(fmaxf(bf2f((unsigned short)pv[5]) + bf2f((unsigned short)dv[5]) + bb.y, 0.f));
        hv[6] = (short)fbf(fmaxf(bf2f((unsigned short)pv[6]) + bf2f((unsigned short)dv[6]) + bb.z, 0.f));
        hv[7] = (short)fbf(fmaxf(bf2f((unsigned short)pv[7]) + bf2f((unsigned short)dv[7]) + bb.w, 0.f));
        *(bf16x8*)&h1t[row * 136 + ch * 8] = hv;
    }
    __syncthreads();

    // layer2 MFMA: [64,128] @ [128,64]
    f32x4 acc2[4];
#pragma unroll
    for (int i = 0; i < 4; ++i) acc2[i] = (f32x4){0.f, 0.f, 0.f, 0.f};
#pragma unroll
    for (int kt = 0; kt < 4; ++kt) {
        bf16x8 av = *(const bf16x8*)&h1t[(w * 16 + c) * 136 + kt * 32 + q * 8];
#pragma unroll
        for (int nt = 0; nt < 4; ++nt) {
            bf16x8 bv = *(const bf16x8*)&W2p[(size_t)((kt * 4 + nt) * 64 + l) * 8];
            acc2[nt] = __builtin_amdgcn_mfma_f32_16x16x32_bf16(av, bv, acc2[nt], 0, 0, 0);
        }
    }
    __syncthreads();   // h1 reads done; h2 aliases

#pragma unroll
    for (int nt = 0; nt < 4; ++nt) {
        float bv = b2[nt * 16 + c];
#pragma unroll
        for (int r = 0; r < 4; ++r)
            h2s[(w * 16 + q * 4 + r) * 65 + nt * 16 + c] = fmaxf(acc2[nt][r] + bv, 0.f);
    }
    __syncthreads();

    if (t < 64) {
        float a = b3[0];
#pragma unroll 8
        for (int kk = 0; kk < 64; ++kk)
            a += h2s[t * 65 + kk] * W3[kk];
        rating[csr_eid[e0 + t]] = 4.f / (1.f + __expf(-a)) + 1.f;
    }
}

extern "C" void kernel_launch(void* const* d_in, const int* in_sizes, int n_in,
                              void* d_out, int out_size, void* d_ws, size_t ws_size,
                              hipStream_t stream) {
    const int*   ei  = (const int*)d_in[0];    // [2, E]
    const float* x   = (const float*)d_in[2];
    const float* mem = (const float*)d_in[3];
    const float* Wq  = (const float*)d_in[4];
    const float* bq  = (const float*)d_in[5];
    const float* Wk  = (const float*)d_in[6];
    const float* bk  = (const float*)d_in[7];
    const float* Wv  = (const float*)d_in[8];
    const float* bv  = (const float*)d_in[9];
    const float* Ws  = (const float*)d_in[10];
    const float* bs  = (const float*)d_in[11];
    const float* W1  = (const float*)d_in[12];
    const float* b1  = (const float*)d_in[13];
    const float* W2  = (const float*)d_in[14];
    const float* b2  = (const float*)d_in[15];
    const float* W3  = (const float*)d_in[16];
    const float* b3  = (const float*)d_in[17];
    float* rating = (float*)d_out;

    // Workspace (~237 MB):
    //   Q  [N,256] bf16 (becomes `out`)                 51.2 MB
    //   KV [N,512] bf16 (lane-interleaved K|V; PD after attn) 102.4 MB
    //   S  [N,256] bf16                                 51.2 MB
    //   H  [N,128] bf16 (x+mem)                         25.6 MB
    //   rp, deg, cursor, csr_*, bsum, packs             ~6.8 MB
    unsigned short* Q = (unsigned short*)d_ws;
    const size_t NHDe = (size_t)N_NODES * HD;   // 25.6M elements
    unsigned short* KV = Q + NHDe;              // N*512 elements
    unsigned short* S  = KV + 2 * NHDe;
    unsigned short* H  = S + NHDe;              // N*128 elements
    int* rp      = (int*)(H + (size_t)N_NODES * HID);
    int* deg     = rp + N_NODES;
    int* cursor  = deg + N_NODES;
    int* csr_src = cursor + N_NODES;
    int* csr_dst = csr_src + N_EDGES;
    int* csr_eid = csr_dst + N_EDGES;
    int* bsum    = csr_eid + N_EDGES;
    unsigned short* Wp  = (unsigned short*)(bsum + 128);
    unsigned short* Wcp = Wp + 16384 * 8;
    unsigned short* W2p = Wcp + 8192 * 8;
    unsigned short* PD  = KV;   // KV table dead after attention

    const int nblk  = (N_NODES + 255) / 256;
    const int eblk  = (N_EDGES + 255) / 256;
    const int wgrid = (N_NODES + 3) / 4;
    const int pblk  = (N_NODES * HID / 8 + 255) / 256;   // 6250

    // CSR build + weight packing
    init_zero<<<nblk, 256, 0, stream>>>(deg, cursor);
    k_deg<<<eblk, 256, 0, stream>>>(ei, deg);
    k_scan1<<<NB_SCAN, 256, 0, stream>>>(deg, rp, bsum);
    k_scan2<<<1, 256, 0, stream>>>(bsum);
    k_bucket<<<eblk, 256, 0, stream>>>(ei, rp, bsum, cursor, csr_src, csr_dst, csr_eid);
    pack_all<<<100, 256, 0, stream>>>(Wq, Wk, Wv, Ws, W1, W2, Wp, Wcp, W2p);

    // H = bf16(x + mem), one streaming pass
    k_pre<<<pblk, 256, 0, stream>>>(x, mem, H);

    // projections: z split across gridDim.y (Q / K->KV / V->KV / S)
    gemm4<<<dim3((N_NODES + 63) / 64, 4), dim3(256), 0, stream>>>(
        H, Wp, bq, bk, bv, bs, Q, KV, S);

    // fused attention (no-max softmax, lane-interleaved KV); out overwrites Q
    k_attn<<<wgrid, 256, 0, stream>>>(rp, bsum, deg, csr_src, Q, KV, S, Q);

    // node-level PD GEMM (layer-1 factorization); PD overwrites KV
    pd_gemm<<<(N_NODES + 63) / 64, 256, 0, stream>>>(Q, Wcp, PD);

    // light edge MLP in CSR order
    edge_mlp_pd<<<N_EDGES / 64, 256, 0, stream>>>(
        csr_src, csr_dst, csr_eid, PD, b1, W2p, b2, W3, b3, rating);
}

// Round 4
// 422.680 us; speedup vs baseline: 1.0794x; 1.0794x over previous
//
#include <hip/hip_runtime.h>
#include <math.h>

#define N_NODES 100000
#define N_EDGES 400000
#define HID 128
#define HEADS 4
#define OUT_C 64
#define HD 256   // HEADS*OUT_C
#define SCAN_CHUNK 1024
#define NB_SCAN ((N_NODES + SCAN_CHUNK - 1) / SCAN_CHUNK)   // 98
#define SLAB_STRIDE 4356   // ushorts per wave slab region (64*68 + 4 pad, breaks bank alias)

typedef __attribute__((ext_vector_type(8))) short bf16x8;   // 8 bf16 = 4 VGPRs
typedef __attribute__((ext_vector_type(4))) float f32x4;

// fp32 -> bf16 round-to-nearest-even
__device__ __forceinline__ unsigned short fbf(float f) {
    unsigned u = __float_as_uint(f);
    unsigned r = (u + 0x7fffu + ((u >> 16) & 1u)) >> 16;
    return (unsigned short)r;
}
__device__ __forceinline__ float bf2f(unsigned short u) {
    return __uint_as_float(((unsigned)u) << 16);
}

// async global->LDS, 16B per lane; LDS dest = wave-uniform base + lane*16
__device__ __forceinline__ void gl_lds16(const void* g, void* l) {
    __builtin_amdgcn_global_load_lds(
        (const __attribute__((address_space(1))) unsigned int*)g,
        (__attribute__((address_space(3))) unsigned int*)l,
        16, 0, 0);
}

// ---------- CSR build: degree count ----------
__global__ __launch_bounds__(256) void k_deg(const int* __restrict__ ei,
                                             int* __restrict__ deg) {
    int e = blockIdx.x * 256 + threadIdx.x;
    if (e < N_EDGES) atomicAdd(&deg[ei[N_EDGES + e]], 1);
}

// ---------- scan 1 ----------
__global__ __launch_bounds__(256) void k_scan1(const int* __restrict__ deg,
                                               int* __restrict__ rp,
                                               int* __restrict__ bsum) {
    __shared__ int ts[256];
    int b = blockIdx.x, t = threadIdx.x;
    int base = b * SCAN_CHUNK + t * 4;
    int vv[4];
    int s = 0;
#pragma unroll
    for (int i = 0; i < 4; ++i) {
        int d = (base + i < N_NODES) ? deg[base + i] : 0;
        vv[i] = s;
        s += d;
    }
    ts[t] = s;
    __syncthreads();
    for (int off = 1; off < 256; off <<= 1) {
        int x = (t >= off) ? ts[t - off] : 0;
        __syncthreads();
        ts[t] += x;
        __syncthreads();
    }
    int ex = ts[t] - s;
#pragma unroll
    for (int i = 0; i < 4; ++i)
        if (base + i < N_NODES) rp[base + i] = ex + vv[i];
    if (t == 255) bsum[b] = ts[255];
}

// ---------- scan 2 ----------
__global__ __launch_bounds__(256) void k_scan2(int* __restrict__ bsum) {
    __shared__ int ts[256];
    int t = threadIdx.x;
    int v = (t < NB_SCAN) ? bsum[t] : 0;
    ts[t] = v;
    __syncthreads();
    for (int off = 1; off < 256; off <<= 1) {
        int x = (t >= off) ? ts[t - off] : 0;
        __syncthreads();
        ts[t] += x;
        __syncthreads();
    }
    if (t < NB_SCAN) bsum[t] = ts[t] - v;
}

// ---------- bucket: fill csr_src / csr_dst / csr_eid (rp finalized inline via bsum) ----------
__global__ __launch_bounds__(256) void k_bucket(const int* __restrict__ ei,
                                                const int* __restrict__ rp,
                                                const int* __restrict__ bsum,
                                                int* __restrict__ cursor,
                                                int* __restrict__ csr_src,
                                                int* __restrict__ csr_dst,
                                                int* __restrict__ csr_eid) {
    int e = blockIdx.x * 256 + threadIdx.x;
    if (e >= N_EDGES) return;
    int src = ei[e];
    int d   = ei[N_EDGES + e];
    int idx = atomicAdd(&cursor[d], 1);
    int s   = rp[d] + bsum[d >> 10] + idx;
    csr_src[s] = src;
    csr_dst[s] = d;
    csr_eid[s] = e;
}

// ---------- merged weight packing ----------
__global__ __launch_bounds__(256) void pack_all(
    const float* __restrict__ Wq, const float* __restrict__ Wk,
    const float* __restrict__ Wv, const float* __restrict__ Ws,
    const float* __restrict__ W1, const float* __restrict__ W2,
    unsigned short* __restrict__ Wp, unsigned short* __restrict__ Wcp,
    unsigned short* __restrict__ W2p) {
    int i = blockIdx.x * 256 + threadIdx.x;   // 25600 total
    int lane = i & 63;
    int q = lane >> 4, c = lane & 15;
    if (i < 16384) {
        int nt = (i >> 6) & 15, kt = (i >> 10) & 3, z = i >> 12;
        const float* W = (z == 0) ? Wq : (z == 1) ? Wk : (z == 2) ? Wv : Ws;
#pragma unroll
        for (int j = 0; j < 8; ++j)
            Wp[i * 8 + j] = fbf(W[(kt * 32 + q * 8 + j) * HD + nt * 16 + c]);
    } else if (i < 24576) {
        int ii = i - 16384;
        int nt = (ii >> 6) & 15, kt = ii >> 10;
        int n = nt * 16 + c;
#pragma unroll
        for (int j = 0; j < 8; ++j) {
            int k = kt * 32 + q * 8 + j;
            float v = (n < 128) ? W1[k * 128 + n] : W1[(k + 256) * 128 + (n - 128)];
            Wcp[ii * 8 + j] = fbf(v);
        }
    } else if (i < 25600) {
        int ii = i - 24576;
        int nt = (ii >> 6) & 3, kt = ii >> 8;
#pragma unroll
        for (int j = 0; j < 8; ++j)
            W2p[ii * 8 + j] = fbf(W2[(kt * 32 + q * 8 + j) * 64 + nt * 16 + c]);
    }
}

// ---------- K_pre: H = bf16(x + mem), one streaming pass ----------
__global__ __launch_bounds__(256) void k_pre(const float* __restrict__ x,
                                             const float* __restrict__ mem,
                                             unsigned short* __restrict__ H) {
    int idx = blockIdx.x * 256 + threadIdx.x;      // chunk of 8 elems
    if (idx >= N_NODES * HID / 8) return;          // 1,600,000 chunks
    const float4* x4 = (const float4*)x;
    const float4* m4 = (const float4*)mem;
    float4 a0 = x4[(size_t)idx * 2],     a1 = x4[(size_t)idx * 2 + 1];
    float4 b0 = m4[(size_t)idx * 2],     b1 = m4[(size_t)idx * 2 + 1];
    bf16x8 hv;
    hv[0] = (short)fbf(a0.x + b0.x); hv[1] = (short)fbf(a0.y + b0.y);
    hv[2] = (short)fbf(a0.z + b0.z); hv[3] = (short)fbf(a0.w + b0.w);
    hv[4] = (short)fbf(a1.x + b1.x); hv[5] = (short)fbf(a1.y + b1.y);
    hv[6] = (short)fbf(a1.z + b1.z); hv[7] = (short)fbf(a1.w + b1.w);
    *(bf16x8*)&H[(size_t)idx * 8] = hv;
}

// ---------- gemm4 helpers ----------
__device__ __forceinline__ void mfma_pass(f32x4 acc[4][4], const short* As,
        const unsigned short* __restrict__ Wp, int z, int w, int l, int q, int c) {
#pragma unroll
    for (int mt = 0; mt < 4; ++mt)
#pragma unroll
        for (int nt = 0; nt < 4; ++nt) acc[mt][nt] = (f32x4){0.f, 0.f, 0.f, 0.f};
#pragma unroll
    for (int kt = 0; kt < 4; ++kt) {
        bf16x8 af[4];
#pragma unroll
        for (int mt = 0; mt < 4; ++mt) {
            int row  = mt * 16 + c;
            int slot = (kt * 4 + q) ^ (row & 7);
            af[mt] = *(const bf16x8*)&As[row * 128 + slot * 8];
        }
#pragma unroll
        for (int nt = 0; nt < 4; ++nt) {
            bf16x8 bw8 = *(const bf16x8*)&Wp[(size_t)(((z * 4 + kt) * 16 + w * 4 + nt) * 64 + l) * 8];
#pragma unroll
            for (int mt = 0; mt < 4; ++mt)
                acc[mt][nt] = __builtin_amdgcn_mfma_f32_16x16x32_bf16(af[mt], bw8, acc[mt][nt], 0, 0, 0);
        }
    }
}

__device__ __forceinline__ void slab_store(short* slab, const f32x4 acc[4][4],
        const float bb[4], int q, int c) {
#pragma unroll
    for (int nt = 0; nt < 4; ++nt)
#pragma unroll
        for (int mt = 0; mt < 4; ++mt)
#pragma unroll
            for (int r = 0; r < 4; ++r)
                slab[(mt * 16 + q * 4 + r) * 68 + nt * 16 + c] =
                    (short)fbf(acc[mt][nt][r] + bb[nt]);
}

__device__ __forceinline__ void store_rows(unsigned short* __restrict__ O,
        const short* slab, int m0, int w, int l) {
    const int srow = l >> 3, schk = l & 7;
#pragma unroll
    for (int j = 0; j < 8; ++j) {
        int row = j * 8 + srow;
        int gr  = m0 + row;
        if (gr < N_NODES)
            *(bf16x8*)&O[(size_t)gr * HD + w * 64 + schk * 8] =
                *(const bf16x8*)&slab[row * 68 + schk * 8];
    }
}

// ---------- K1: projection GEMM, 2-way y split ----------
// y=0: Q pass then S pass (plain [N,256] stores)
// y=1: K pass then V pass; final store merges K|V into lane-interleaved KV:
//      chunk l of row n (16 B at KV[n*512 + l*8]) = [K[4l..4l+4) | V[4l..4l+4)]
//      -> each 16 B written once, full width, single wave. Fixes the 8 B
//      partial-sector write amplification (WRITE_SIZE 300 -> ~205 MB).
__global__ __launch_bounds__(256, 3) void gemm4(
    const unsigned short* __restrict__ H,
    const unsigned short* __restrict__ Wp,
    const float* __restrict__ bq, const float* __restrict__ bk,
    const float* __restrict__ bv, const float* __restrict__ bs,
    unsigned short* __restrict__ Q, unsigned short* __restrict__ KV,
    unsigned short* __restrict__ S)
{
    __shared__ __align__(16) short As[64 * 128];           // 16 KB, lives across both passes
    __shared__ __align__(16) short Slab[4 * SLAB_STRIDE];  // 34848 B

    const int t = threadIdx.x;
    const int w = t >> 6, l = t & 63;
    const int q = l >> 4, c = l & 15;
    const int y  = blockIdx.y;          // 0: Q,S   1: K,V
    const int m0 = blockIdx.x * 64;

    // async stage H tile 64x128 bf16: linear LDS dest, XOR-pre-swizzled global src
#pragma unroll
    for (int i = 0; i < 4; ++i) {
        int rbase = w * 16 + i * 4;
        int r  = rbase + (l >> 4);
        int gr = m0 + r; if (gr >= N_NODES) gr = N_NODES - 1;   // clamp; stores guarded
        int ks = (l & 15) ^ (r & 7);
        gl_lds16(&H[(size_t)gr * HID + ks * 8], &As[rbase * 128]);
    }

    const int   zA  = (y == 0) ? 0 : 1;
    const int   zB  = (y == 0) ? 3 : 2;
    const float* bA = (y == 0) ? bq : bk;
    const float* bB = (y == 0) ? bs : bv;
    float bbA[4], bbB[4];
#pragma unroll
    for (int nt = 0; nt < 4; ++nt) {
        bbA[nt] = bA[w * 64 + nt * 16 + c];
        bbB[nt] = bB[w * 64 + nt * 16 + c];
    }

    __syncthreads();   // As ready

    short* slab = &Slab[w * SLAB_STRIDE];
    f32x4 acc[4][4];
    ushort4 kreg[16];
    const int koff = (l & 15) * 4;
    const short* cslab = &Slab[(l >> 4) * SLAB_STRIDE];   // cross-wave chunk source

    // ---- pass A (Q or K) ----
    mfma_pass(acc, As, Wp, zA, w, l, q, c);
    slab_store(slab, acc, bbA, q, c);
    if (y == 0) {
        store_rows(Q, slab, m0, w, l);        // own-wave slab read: no barrier needed
    } else {
        __syncthreads();                      // K slab visible to all waves
#pragma unroll
        for (int i = 0; i < 16; ++i)          // capture K chunks for rows w*16..+16
            kreg[i] = *(const ushort4*)&cslab[(w * 16 + i) * 68 + koff];
        __syncthreads();                      // all K reads done before V overwrites
    }

    // ---- pass B (S or V) ----
    mfma_pass(acc, As, Wp, zB, w, l, q, c);
    slab_store(slab, acc, bbB, q, c);
    if (y == 0) {
        store_rows(S, slab, m0, w, l);
    } else {
        __syncthreads();                      // V slab visible
#pragma unroll
        for (int i = 0; i < 16; ++i) {
            int gr = m0 + w * 16 + i;
            ushort4 vr = *(const ushort4*)&cslab[(w * 16 + i) * 68 + koff];
            if (gr < N_NODES) {
                bf16x8 ov;
                ov[0] = (short)kreg[i].x; ov[1] = (short)kreg[i].y;
                ov[2] = (short)kreg[i].z; ov[3] = (short)kreg[i].w;
                ov[4] = (short)vr.x;      ov[5] = (short)vr.y;
                ov[6] = (short)vr.z;      ov[7] = (short)vr.w;
                *(bf16x8*)&KV[(size_t)gr * 512 + l * 8] = ov;
            }
        }
    }
}

// ---------- K2: fused attention, one wave per node ----------
// KV lane-interleaved: lane l reads ONE 16 B chunk = [K[l*4..+4) | V[l*4..+4)]
// No-max softmax (scores tiny, shift-invariant); 4/2/1-edge unroll ladder.
__global__ __launch_bounds__(256) void k_attn(
    const int* __restrict__ rp, const int* __restrict__ bsum,
    const int* __restrict__ deg, const int* __restrict__ csr_src,
    const unsigned short* __restrict__ Q, const unsigned short* __restrict__ KV,
    const unsigned short* __restrict__ S,
    unsigned short* __restrict__ out)
{
    int node = blockIdx.x * 4 + (threadIdx.x >> 6);
    int l = threadIdx.x & 63;
    if (node >= N_NODES) return;
    int start = rp[node] + bsum[node >> 10];
    int cnt   = deg[node];

    float q0, q1, q2, q3;   // pre-scaled by 1/sqrt(64) = 0.125 (exact pow2)
    {
        ushort4 u = *(const ushort4*)&Q[(size_t)node * HD + l * 4];
        q0 = bf2f(u.x) * 0.125f; q1 = bf2f(u.y) * 0.125f;
        q2 = bf2f(u.z) * 0.125f; q3 = bf2f(u.w) * 0.125f;
    }

    float d = 0.f;
    float a0 = 0.f, a1 = 0.f, a2 = 0.f, a3 = 0.f;

    int i = 0;
    for (; i + 4 <= cnt; i += 4) {
        int s0 = csr_src[start + i];
        int s1 = csr_src[start + i + 1];
        int s2 = csr_src[start + i + 2];
        int s3 = csr_src[start + i + 3];
        bf16x8 k0 = *(const bf16x8*)&KV[(size_t)s0 * 512 + l * 8];
        bf16x8 k1 = *(const bf16x8*)&KV[(size_t)s1 * 512 + l * 8];
        bf16x8 k2 = *(const bf16x8*)&KV[(size_t)s2 * 512 + l * 8];
        bf16x8 k3 = *(const bf16x8*)&KV[(size_t)s3 * 512 + l * 8];
        float sA = q0 * bf2f((unsigned short)k0[0]) + q1 * bf2f((unsigned short)k0[1])
                 + q2 * bf2f((unsigned short)k0[2]) + q3 * bf2f((unsigned short)k0[3]);
        float sB = q0 * bf2f((unsigned short)k1[0]) + q1 * bf2f((unsigned short)k1[1])
                 + q2 * bf2f((unsigned short)k1[2]) + q3 * bf2f((unsigned short)k1[3]);
        float sC = q0 * bf2f((unsigned short)k2[0]) + q1 * bf2f((unsigned short)k2[1])
                 + q2 * bf2f((unsigned short)k2[2]) + q3 * bf2f((unsigned short)k2[3]);
        float sD = q0 * bf2f((unsigned short)k3[0]) + q1 * bf2f((unsigned short)k3[1])
                 + q2 * bf2f((unsigned short)k3[2]) + q3 * bf2f((unsigned short)k3[3]);
        sA += __shfl_xor(sA, 1); sB += __shfl_xor(sB, 1);
        sC += __shfl_xor(sC, 1); sD += __shfl_xor(sD, 1);
        sA += __shfl_xor(sA, 2); sB += __shfl_xor(sB, 2);
        sC += __shfl_xor(sC, 2); sD += __shfl_xor(sD, 2);
        sA += __shfl_xor(sA, 4); sB += __shfl_xor(sB, 4);
        sC += __shfl_xor(sC, 4); sD += __shfl_xor(sD, 4);
        sA += __shfl_xor(sA, 8); sB += __shfl_xor(sB, 8);
        sC += __shfl_xor(sC, 8); sD += __shfl_xor(sD, 8);
        float eA = __expf(sA), eB = __expf(sB), eC = __expf(sC), eD = __expf(sD);
        d += (eA + eB) + (eC + eD);
        a0 += eA * bf2f((unsigned short)k0[4]) + eB * bf2f((unsigned short)k1[4])
            + eC * bf2f((unsigned short)k2[4]) + eD * bf2f((unsigned short)k3[4]);
        a1 += eA * bf2f((unsigned short)k0[5]) + eB * bf2f((unsigned short)k1[5])
            + eC * bf2f((unsigned short)k2[5]) + eD * bf2f((unsigned short)k3[5]);
        a2 += eA * bf2f((unsigned short)k0[6]) + eB * bf2f((unsigned short)k1[6])
            + eC * bf2f((unsigned short)k2[6]) + eD * bf2f((unsigned short)k3[6]);
        a3 += eA * bf2f((unsigned short)k0[7]) + eB * bf2f((unsigned short)k1[7])
            + eC * bf2f((unsigned short)k2[7]) + eD * bf2f((unsigned short)k3[7]);
    }
    if (i + 2 <= cnt) {
        int s0 = csr_src[start + i];
        int s1 = csr_src[start + i + 1];
        bf16x8 k0 = *(const bf16x8*)&KV[(size_t)s0 * 512 + l * 8];
        bf16x8 k1 = *(const bf16x8*)&KV[(size_t)s1 * 512 + l * 8];
        float sA = q0 * bf2f((unsigned short)k0[0]) + q1 * bf2f((unsigned short)k0[1])
                 + q2 * bf2f((unsigned short)k0[2]) + q3 * bf2f((unsigned short)k0[3]);
        float sB = q0 * bf2f((unsigned short)k1[0]) + q1 * bf2f((unsigned short)k1[1])
                 + q2 * bf2f((unsigned short)k1[2]) + q3 * bf2f((unsigned short)k1[3]);
        sA += __shfl_xor(sA, 1); sB += __shfl_xor(sB, 1);
        sA += __shfl_xor(sA, 2); sB += __shfl_xor(sB, 2);
        sA += __shfl_xor(sA, 4); sB += __shfl_xor(sB, 4);
        sA += __shfl_xor(sA, 8); sB += __shfl_xor(sB, 8);
        float eA = __expf(sA), eB = __expf(sB);
        d += eA + eB;
        a0 += eA * bf2f((unsigned short)k0[4]) + eB * bf2f((unsigned short)k1[4]);
        a1 += eA * bf2f((unsigned short)k0[5]) + eB * bf2f((unsigned short)k1[5]);
        a2 += eA * bf2f((unsigned short)k0[6]) + eB * bf2f((unsigned short)k1[6]);
        a3 += eA * bf2f((unsigned short)k0[7]) + eB * bf2f((unsigned short)k1[7]);
        i += 2;
    }
    if (i < cnt) {
        int s0 = csr_src[start + i];
        bf16x8 k0 = *(const bf16x8*)&KV[(size_t)s0 * 512 + l * 8];
        float sA = q0 * bf2f((unsigned short)k0[0]) + q1 * bf2f((unsigned short)k0[1])
                 + q2 * bf2f((unsigned short)k0[2]) + q3 * bf2f((unsigned short)k0[3]);
        sA += __shfl_xor(sA, 1);
        sA += __shfl_xor(sA, 2);
        sA += __shfl_xor(sA, 4);
        sA += __shfl_xor(sA, 8);
        float eA = __expf(sA);
        d += eA;
        a0 += eA * bf2f((unsigned short)k0[4]);
        a1 += eA * bf2f((unsigned short)k0[5]);
        a2 += eA * bf2f((unsigned short)k0[6]);
        a3 += eA * bf2f((unsigned short)k0[7]);
    }

    float inv = 1.f / (d + 1e-16f);
    ushort4 su = *(const ushort4*)&S[(size_t)node * HD + l * 4];
    ushort4 ov = make_ushort4(fbf(bf2f(su.x) + a0 * inv),
                              fbf(bf2f(su.y) + a1 * inv),
                              fbf(bf2f(su.z) + a2 * inv),
                              fbf(bf2f(su.w) + a3 * inv));
    *(ushort4*)&out[(size_t)node * HD + l * 4] = ov;
}

// ---------- K3: PD GEMM — PD[n] = out[n] @ [W1_top | W1_bot],  M=100k K=256 N=256 ----------
// async global_load_lds staging (linear LDS, XOR-pre-swizzled global source)
__global__ __launch_bounds__(256, 4) void pd_gemm(
    const unsigned short* __restrict__ outb,
    const unsigned short* __restrict__ Wcp,
    unsigned short* __restrict__ PD)
{
    __shared__ __align__(16) short sh[4 * 64 * 68];   // 34816 B union:
    short* As = sh;                                    //   As [64][256] swizzled (32 KB)
                                                       //   slab 4 x [64][68] after barrier

    const int t = threadIdx.x;
    const int w = t >> 6, l = t & 63;
    const int q = l >> 4, c = l & 15;
    const int m0 = blockIdx.x * 64;

    // async stage A = out[m0..m0+64, 0..256) bf16: wave w stages rows [w*16, w*16+16)
#pragma unroll
    for (int i = 0; i < 8; ++i) {
        int rbase = w * 16 + i * 2;
        int r  = rbase + (l >> 5);
        int gr = m0 + r; if (gr >= N_NODES) gr = N_NODES - 1;   // clamp; stores guarded
        int s  = (l & 31) ^ (r & 7);
        gl_lds16(&outb[(size_t)gr * HD + s * 8], &As[rbase * 256]);
    }

    f32x4 acc[4][4];
#pragma unroll
    for (int mt = 0; mt < 4; ++mt)
#pragma unroll
        for (int nt = 0; nt < 4; ++nt) acc[mt][nt] = (f32x4){0.f, 0.f, 0.f, 0.f};

    __syncthreads();

#pragma unroll
    for (int kt = 0; kt < 8; ++kt) {
        bf16x8 af[4];
#pragma unroll
        for (int mt = 0; mt < 4; ++mt) {
            int row  = mt * 16 + c;
            int slot = (kt * 4 + q) ^ (row & 7);
            af[mt] = *(const bf16x8*)&As[row * 256 + slot * 8];
        }
#pragma unroll
        for (int nt = 0; nt < 4; ++nt) {
            int ntg = w * 4 + nt;
            bf16x8 bv8 = *(const bf16x8*)&Wcp[(size_t)((kt * 16 + ntg) * 64 + l) * 8];
#pragma unroll
            for (int mt = 0; mt < 4; ++mt)
                acc[mt][nt] = __builtin_amdgcn_mfma_f32_16x16x32_bf16(af[mt], bv8, acc[mt][nt], 0, 0, 0);
        }
    }
    __syncthreads();   // all As reads done; slab aliases As

    short* slab = &sh[w * 64 * 68];
#pragma unroll
    for (int nt = 0; nt < 4; ++nt)
#pragma unroll
        for (int mt = 0; mt < 4; ++mt)
#pragma unroll
            for (int r = 0; r < 4; ++r)
                slab[(mt * 16 + q * 4 + r) * 68 + nt * 16 + c] =
                    (short)fbf(acc[mt][nt][r]);
    const int srow = l >> 3, schk = l & 7;
#pragma unroll
    for (int j = 0; j < 8; ++j) {
        int row = j * 8 + srow;
        int gr = m0 + row;
        if (gr < N_NODES)
            *(bf16x8*)&PD[(size_t)gr * HD + w * 64 + schk * 8] =
                *(const bf16x8*)&slab[row * 68 + schk * 8];
    }
}

// ---------- K5: light edge MLP — h1 = relu(P[src]+D[dst]+b1); layer2 MFMA; layer3 ----------
__global__ __launch_bounds__(256) void edge_mlp_pd(
    const int* __restrict__ csr_src, const int* __restrict__ csr_dst,
    const int* __restrict__ csr_eid,
    const unsigned short* __restrict__ PD,
    const float* __restrict__ b1,
    const unsigned short* __restrict__ W2p, const float* __restrict__ b2,
    const float* __restrict__ W3, const float* __restrict__ b3,
    float* __restrict__ rating)
{
    __shared__ __align__(16) char lds[64 * 136 * 2];   // 17408 B union:
    short* h1t = (short*)lds;                          //   h1 bf16 [64][136]
    float* h2s = (float*)lds;                          //   h2 f32 [64][65] (aliases after barrier)

    const int t = threadIdx.x;
    const int w = t >> 6, l = t & 63;
    const int q = l >> 4, c = l & 15;
    const int e0 = blockIdx.x * 64;

    // stage h1 = relu(P[src] + D[dst] + b1): 64 rows x 128 cols bf16
#pragma unroll
    for (int j = 0; j < 4; ++j) {
        int idx = t + j * 256;          // 1024 chunks of 8 elems
        int row = idx >> 4, ch = idx & 15;
        int src = csr_src[e0 + row];
        int dst = csr_dst[e0 + row];
        bf16x8 pv = *(const bf16x8*)&PD[(size_t)src * HD + ch * 8];
        bf16x8 dv = *(const bf16x8*)&PD[(size_t)dst * HD + 128 + ch * 8];
        float4 ba = *(const float4*)&b1[ch * 8];
        float4 bb = *(const float4*)&b1[ch * 8 + 4];
        bf16x8 hv;
        hv[0] = (short)fbf(fmaxf(bf2f((unsigned short)pv[0]) + bf2f((unsigned short)dv[0]) + ba.x, 0.f));
        hv[1] = (short)fbf(fmaxf(bf2f((unsigned short)pv[1]) + bf2f((unsigned short)dv[1]) + ba.y, 0.f));
        hv[2] = (short)fbf(fmaxf(bf2f((unsigned short)pv[2]) + bf2f((unsigned short)dv[2]) + ba.z, 0.f));
        hv[3] = (short)fbf(fmaxf(bf2f((unsigned short)pv[3]) + bf2f((unsigned short)dv[3]) + ba.w, 0.f));
        hv[4] = (short)fbf(fmaxf(bf2f((unsigned short)pv[4]) + bf2f((unsigned short)dv[4]) + bb.x, 0.f));
        hv[5] = (short)fbf(fmaxf(bf2f((unsigned short)pv[5]) + bf2f((unsigned short)dv[5]) + bb.y, 0.f));
        hv[6] = (short)fbf(fmaxf(bf2f((unsigned short)pv[6]) + bf2f((unsigned short)dv[6]) + bb.z, 0.f));
        hv[7] = (short)fbf(fmaxf(bf2f((unsigned short)pv[7]) + bf2f((unsigned short)dv[7]) + bb.w, 0.f));
        *(bf16x8*)&h1t[row * 136 + ch * 8] = hv;
    }
    __syncthreads();

    // layer2 MFMA: [64,128] @ [128,64]
    f32x4 acc2[4];
#pragma unroll
    for (int i = 0; i < 4; ++i) acc2[i] = (f32x4){0.f, 0.f, 0.f, 0.f};
#pragma unroll
    for (int kt = 0; kt < 4; ++kt) {
        bf16x8 av = *(const bf16x8*)&h1t[(w * 16 + c) * 136 + kt * 32 + q * 8];
#pragma unroll
        for (int nt = 0; nt < 4; ++nt) {
            bf16x8 bv = *(const bf16x8*)&W2p[(size_t)((kt * 4 + nt) * 64 + l) * 8];
            acc2[nt] = __builtin_amdgcn_mfma_f32_16x16x32_bf16(av, bv, acc2[nt], 0, 0, 0);
        }
    }
    __syncthreads();   // h1 reads done; h2 aliases

#pragma unroll
    for (int nt = 0; nt < 4; ++nt) {
        float bv = b2[nt * 16 + c];
#pragma unroll
        for (int r = 0; r < 4; ++r)
            h2s[(w * 16 + q * 4 + r) * 65 + nt * 16 + c] = fmaxf(acc2[nt][r] + bv, 0.f);
    }
    __syncthreads();

    if (t < 64) {
        float a = b3[0];
#pragma unroll 8
        for (int kk = 0; kk < 64; ++kk)
            a += h2s[t * 65 + kk] * W3[kk];
        rating[csr_eid[e0 + t]] = 4.f / (1.f + __expf(-a)) + 1.f;
    }
}

extern "C" void kernel_launch(void* const* d_in, const int* in_sizes, int n_in,
                              void* d_out, int out_size, void* d_ws, size_t ws_size,
                              hipStream_t stream) {
    const int*   ei  = (const int*)d_in[0];    // [2, E]
    const float* x   = (const float*)d_in[2];
    const float* mem = (const float*)d_in[3];
    const float* Wq  = (const float*)d_in[4];
    const float* bq  = (const float*)d_in[5];
    const float* Wk  = (const float*)d_in[6];
    const float* bk  = (const float*)d_in[7];
    const float* Wv  = (const float*)d_in[8];
    const float* bv  = (const float*)d_in[9];
    const float* Ws  = (const float*)d_in[10];
    const float* bs  = (const float*)d_in[11];
    const float* W1  = (const float*)d_in[12];
    const float* b1  = (const float*)d_in[13];
    const float* W2  = (const float*)d_in[14];
    const float* b2  = (const float*)d_in[15];
    const float* W3  = (const float*)d_in[16];
    const float* b3  = (const float*)d_in[17];
    float* rating = (float*)d_out;

    // Workspace (~237 MB):
    //   Q  [N,256] bf16 (becomes `out`)                      51.2 MB
    //   KV [N,512] bf16 (lane-interleaved K|V; PD after attn) 102.4 MB
    //   S  [N,256] bf16                                      51.2 MB
    //   H  [N,128] bf16 (x+mem)                              25.6 MB
    //   rp, deg, cursor, csr_*, bsum, packs                  ~6.8 MB
    unsigned short* Q = (unsigned short*)d_ws;
    const size_t NHDe = (size_t)N_NODES * HD;   // 25.6M elements
    unsigned short* KV = Q + NHDe;              // N*512 elements
    unsigned short* S  = KV + 2 * NHDe;
    unsigned short* H  = S + NHDe;              // N*128 elements
    int* rp      = (int*)(H + (size_t)N_NODES * HID);
    int* deg     = rp + N_NODES;
    int* cursor  = deg + N_NODES;
    int* csr_src = cursor + N_NODES;
    int* csr_dst = csr_src + N_EDGES;
    int* csr_eid = csr_dst + N_EDGES;
    int* bsum    = csr_eid + N_EDGES;
    unsigned short* Wp  = (unsigned short*)(bsum + 128);
    unsigned short* Wcp = Wp + 16384 * 8;
    unsigned short* W2p = Wcp + 8192 * 8;
    unsigned short* PD  = KV;   // KV table dead after attention

    const int eblk  = (N_EDGES + 255) / 256;
    const int wgrid = (N_NODES + 3) / 4;
    const int pblk  = (N_NODES * HID / 8 + 255) / 256;   // 6250

    // CSR build + weight packing (deg and cursor are adjacent -> one memset)
    hipMemsetAsync(deg, 0, sizeof(int) * 2 * N_NODES, stream);
    k_deg<<<eblk, 256, 0, stream>>>(ei, deg);
    k_scan1<<<NB_SCAN, 256, 0, stream>>>(deg, rp, bsum);
    k_scan2<<<1, 256, 0, stream>>>(bsum);
    k_bucket<<<eblk, 256, 0, stream>>>(ei, rp, bsum, cursor, csr_src, csr_dst, csr_eid);
    pack_all<<<100, 256, 0, stream>>>(Wq, Wk, Wv, Ws, W1, W2, Wp, Wcp, W2p);

    // H = bf16(x + mem), one streaming pass
    k_pre<<<pblk, 256, 0, stream>>>(x, mem, H);

    // projections: y=0 -> Q,S ; y=1 -> K,V (merged interleaved store)
    gemm4<<<dim3((N_NODES + 63) / 64, 2), dim3(256), 0, stream>>>(
        H, Wp, bq, bk, bv, bs, Q, KV, S);

    // fused attention (no-max softmax, lane-interleaved KV); out overwrites Q
    k_attn<<<wgrid, 256, 0, stream>>>(rp, bsum, deg, csr_src, Q, KV, S, Q);

    // node-level PD GEMM (layer-1 factorization); PD overwrites KV
    pd_gemm<<<(N_NODES + 63) / 64, 256, 0, stream>>>(Q, Wcp, PD);

    // light edge MLP in CSR order
    edge_mlp_pd<<<N_EDGES / 64, 256, 0, stream>>>(
        csr_src, csr_dst, csr_eid, PD, b1, W2p, b2, W3, b3, rating);
}

// Round 5
// 416.226 us; speedup vs baseline: 1.0962x; 1.0155x over previous
//
#include <hip/hip_runtime.h>
#include <math.h>

#define N_NODES 100000
#define N_EDGES 400000
#define HID 128
#define HEADS 4
#define OUT_C 64
#define HD 256   // HEADS*OUT_C
#define SCAN_CHUNK 1024
#define NB_SCAN ((N_NODES + SCAN_CHUNK - 1) / SCAN_CHUNK)   // 98
#define SLAB_STRIDE 4356   // gemm4 per-wave slab stride (ushorts)
#define PSLAB_W 2576       // attn_pd per-wave slab stride (ushorts; 64*40 + 16 pad)

typedef __attribute__((ext_vector_type(8))) short bf16x8;   // 8 bf16 = 4 VGPRs
typedef __attribute__((ext_vector_type(4))) float f32x4;

// fp32 -> bf16 round-to-nearest-even
__device__ __forceinline__ unsigned short fbf(float f) {
    unsigned u = __float_as_uint(f);
    unsigned r = (u + 0x7fffu + ((u >> 16) & 1u)) >> 16;
    return (unsigned short)r;
}
__device__ __forceinline__ float bf2f(unsigned short u) {
    return __uint_as_float(((unsigned)u) << 16);
}

// async global->LDS, 16B per lane; LDS dest = wave-uniform base + lane*16
__device__ __forceinline__ void gl_lds16(const void* g, void* l) {
    __builtin_amdgcn_global_load_lds(
        (const __attribute__((address_space(1))) unsigned int*)g,
        (__attribute__((address_space(3))) unsigned int*)l,
        16, 0, 0);
}

// ---------- CSR build: degree count ----------
__global__ __launch_bounds__(256) void k_deg(const int* __restrict__ ei,
                                             int* __restrict__ deg) {
    int e = blockIdx.x * 256 + threadIdx.x;
    if (e < N_EDGES) atomicAdd(&deg[ei[N_EDGES + e]], 1);
}

// ---------- scan 1 ----------
__global__ __launch_bounds__(256) void k_scan1(const int* __restrict__ deg,
                                               int* __restrict__ rp,
                                               int* __restrict__ bsum) {
    __shared__ int ts[256];
    int b = blockIdx.x, t = threadIdx.x;
    int base = b * SCAN_CHUNK + t * 4;
    int vv[4];
    int s = 0;
#pragma unroll
    for (int i = 0; i < 4; ++i) {
        int d = (base + i < N_NODES) ? deg[base + i] : 0;
        vv[i] = s;
        s += d;
    }
    ts[t] = s;
    __syncthreads();
    for (int off = 1; off < 256; off <<= 1) {
        int x = (t >= off) ? ts[t - off] : 0;
        __syncthreads();
        ts[t] += x;
        __syncthreads();
    }
    int ex = ts[t] - s;
#pragma unroll
    for (int i = 0; i < 4; ++i)
        if (base + i < N_NODES) rp[base + i] = ex + vv[i];
    if (t == 255) bsum[b] = ts[255];
}

// ---------- scan 2 ----------
__global__ __launch_bounds__(256) void k_scan2(int* __restrict__ bsum) {
    __shared__ int ts[256];
    int t = threadIdx.x;
    int v = (t < NB_SCAN) ? bsum[t] : 0;
    ts[t] = v;
    __syncthreads();
    for (int off = 1; off < 256; off <<= 1) {
        int x = (t >= off) ? ts[t - off] : 0;
        __syncthreads();
        ts[t] += x;
        __syncthreads();
    }
    if (t < NB_SCAN) bsum[t] = ts[t] - v;
}

// ---------- bucket: fill csr_src / csr_dst / csr_eid (rp finalized inline via bsum) ----------
__global__ __launch_bounds__(256) void k_bucket(const int* __restrict__ ei,
                                                const int* __restrict__ rp,
                                                const int* __restrict__ bsum,
                                                int* __restrict__ cursor,
                                                int* __restrict__ csr_src,
                                                int* __restrict__ csr_dst,
                                                int* __restrict__ csr_eid) {
    int e = blockIdx.x * 256 + threadIdx.x;
    if (e >= N_EDGES) return;
    int src = ei[e];
    int d   = ei[N_EDGES + e];
    int idx = atomicAdd(&cursor[d], 1);
    int s   = rp[d] + bsum[d >> 10] + idx;
    csr_src[s] = src;
    csr_dst[s] = d;
    csr_eid[s] = e;
}

// ---------- merged weight packing ----------
__global__ __launch_bounds__(256) void pack_all(
    const float* __restrict__ Wq, const float* __restrict__ Wk,
    const float* __restrict__ Wv, const float* __restrict__ Ws,
    const float* __restrict__ W1, const float* __restrict__ W2,
    unsigned short* __restrict__ Wp, unsigned short* __restrict__ Wcp,
    unsigned short* __restrict__ W2p) {
    int i = blockIdx.x * 256 + threadIdx.x;   // 25600 total
    int lane = i & 63;
    int q = lane >> 4, c = lane & 15;
    if (i < 16384) {
        int nt = (i >> 6) & 15, kt = (i >> 10) & 3, z = i >> 12;
        const float* W = (z == 0) ? Wq : (z == 1) ? Wk : (z == 2) ? Wv : Ws;
#pragma unroll
        for (int j = 0; j < 8; ++j)
            Wp[i * 8 + j] = fbf(W[(kt * 32 + q * 8 + j) * HD + nt * 16 + c]);
    } else if (i < 24576) {
        int ii = i - 16384;
        int nt = (ii >> 6) & 15, kt = ii >> 10;
        int n = nt * 16 + c;
#pragma unroll
        for (int j = 0; j < 8; ++j) {
            int k = kt * 32 + q * 8 + j;
            float v = (n < 128) ? W1[k * 128 + n] : W1[(k + 256) * 128 + (n - 128)];
            Wcp[ii * 8 + j] = fbf(v);
        }
    } else if (i < 25600) {
        int ii = i - 24576;
        int nt = (ii >> 6) & 3, kt = ii >> 8;
#pragma unroll
        for (int j = 0; j < 8; ++j)
            W2p[ii * 8 + j] = fbf(W2[(kt * 32 + q * 8 + j) * 64 + nt * 16 + c]);
    }
}

// ---------- K_pre: H = bf16(x + mem), one streaming pass ----------
__global__ __launch_bounds__(256) void k_pre(const float* __restrict__ x,
                                             const float* __restrict__ mem,
                                             unsigned short* __restrict__ H) {
    int idx = blockIdx.x * 256 + threadIdx.x;      // chunk of 8 elems
    if (idx >= N_NODES * HID / 8) return;          // 1,600,000 chunks
    const float4* x4 = (const float4*)x;
    const float4* m4 = (const float4*)mem;
    float4 a0 = x4[(size_t)idx * 2],     a1 = x4[(size_t)idx * 2 + 1];
    float4 b0 = m4[(size_t)idx * 2],     b1 = m4[(size_t)idx * 2 + 1];
    bf16x8 hv;
    hv[0] = (short)fbf(a0.x + b0.x); hv[1] = (short)fbf(a0.y + b0.y);
    hv[2] = (short)fbf(a0.z + b0.z); hv[3] = (short)fbf(a0.w + b0.w);
    hv[4] = (short)fbf(a1.x + b1.x); hv[5] = (short)fbf(a1.y + b1.y);
    hv[6] = (short)fbf(a1.z + b1.z); hv[7] = (short)fbf(a1.w + b1.w);
    *(bf16x8*)&H[(size_t)idx * 8] = hv;
}

// ---------- gemm4 helpers ----------
__device__ __forceinline__ void mfma_pass(f32x4 acc[4][4], const short* As,
        const unsigned short* __restrict__ Wp, int z, int w, int l, int q, int c) {
#pragma unroll
    for (int mt = 0; mt < 4; ++mt)
#pragma unroll
        for (int nt = 0; nt < 4; ++nt) acc[mt][nt] = (f32x4){0.f, 0.f, 0.f, 0.f};
#pragma unroll
    for (int kt = 0; kt < 4; ++kt) {
        bf16x8 af[4];
#pragma unroll
        for (int mt = 0; mt < 4; ++mt) {
            int row  = mt * 16 + c;
            int slot = (kt * 4 + q) ^ (row & 7);
            af[mt] = *(const bf16x8*)&As[row * 128 + slot * 8];
        }
#pragma unroll
        for (int nt = 0; nt < 4; ++nt) {
            bf16x8 bw8 = *(const bf16x8*)&Wp[(size_t)(((z * 4 + kt) * 16 + w * 4 + nt) * 64 + l) * 8];
#pragma unroll
            for (int mt = 0; mt < 4; ++mt)
                acc[mt][nt] = __builtin_amdgcn_mfma_f32_16x16x32_bf16(af[mt], bw8, acc[mt][nt], 0, 0, 0);
        }
    }
}

__device__ __forceinline__ void slab_store(short* slab, const f32x4 acc[4][4],
        const float bb[4], int q, int c) {
#pragma unroll
    for (int nt = 0; nt < 4; ++nt)
#pragma unroll
        for (int mt = 0; mt < 4; ++mt)
#pragma unroll
            for (int r = 0; r < 4; ++r)
                slab[(mt * 16 + q * 4 + r) * 68 + nt * 16 + c] =
                    (short)fbf(acc[mt][nt][r] + bb[nt]);
}

__device__ __forceinline__ void store_rows(unsigned short* __restrict__ O,
        const short* slab, int m0, int w, int l) {
    const int srow = l >> 3, schk = l & 7;
#pragma unroll
    for (int j = 0; j < 8; ++j) {
        int row = j * 8 + srow;
        int gr  = m0 + row;
        if (gr < N_NODES)
            *(bf16x8*)&O[(size_t)gr * HD + w * 64 + schk * 8] =
                *(const bf16x8*)&slab[row * 68 + schk * 8];
    }
}

// ---------- K1: projection GEMM, 2-way y split ----------
// y=0: Q pass then S pass (plain [N,256] stores)
// y=1: K then V; merge store -> lane-interleaved KV (each 16 B written once)
__global__ __launch_bounds__(256, 3) void gemm4(
    const unsigned short* __restrict__ H,
    const unsigned short* __restrict__ Wp,
    const float* __restrict__ bq, const float* __restrict__ bk,
    const float* __restrict__ bv, const float* __restrict__ bs,
    unsigned short* __restrict__ Q, unsigned short* __restrict__ KV,
    unsigned short* __restrict__ S)
{
    __shared__ __align__(16) short As[64 * 128];           // 16 KB, lives across both passes
    __shared__ __align__(16) short Slab[4 * SLAB_STRIDE];  // 34848 B

    const int t = threadIdx.x;
    const int w = t >> 6, l = t & 63;
    const int q = l >> 4, c = l & 15;
    const int y  = blockIdx.y;          // 0: Q,S   1: K,V
    const int m0 = blockIdx.x * 64;

    // async stage H tile 64x128 bf16: linear LDS dest, XOR-pre-swizzled global src
#pragma unroll
    for (int i = 0; i < 4; ++i) {
        int rbase = w * 16 + i * 4;
        int r  = rbase + (l >> 4);
        int gr = m0 + r; if (gr >= N_NODES) gr = N_NODES - 1;   // clamp; stores guarded
        int ks = (l & 15) ^ (r & 7);
        gl_lds16(&H[(size_t)gr * HID + ks * 8], &As[rbase * 128]);
    }

    const int   zA  = (y == 0) ? 0 : 1;
    const int   zB  = (y == 0) ? 3 : 2;
    const float* bA = (y == 0) ? bq : bk;
    const float* bB = (y == 0) ? bs : bv;
    float bbA[4], bbB[4];
#pragma unroll
    for (int nt = 0; nt < 4; ++nt) {
        bbA[nt] = bA[w * 64 + nt * 16 + c];
        bbB[nt] = bB[w * 64 + nt * 16 + c];
    }

    __syncthreads();   // As ready

    short* slab = &Slab[w * SLAB_STRIDE];
    f32x4 acc[4][4];
    ushort4 kreg[16];
    const int koff = (l & 15) * 4;
    const short* cslab = &Slab[(l >> 4) * SLAB_STRIDE];   // cross-wave chunk source

    // ---- pass A (Q or K) ----
    mfma_pass(acc, As, Wp, zA, w, l, q, c);
    slab_store(slab, acc, bbA, q, c);
    if (y == 0) {
        store_rows(Q, slab, m0, w, l);        // own-wave slab read: no barrier needed
    } else {
        __syncthreads();                      // K slab visible to all waves
#pragma unroll
        for (int i = 0; i < 16; ++i)          // capture K chunks for rows w*16..+16
            kreg[i] = *(const ushort4*)&cslab[(w * 16 + i) * 68 + koff];
        __syncthreads();                      // all K reads done before V overwrites
    }

    // ---- pass B (S or V) ----
    mfma_pass(acc, As, Wp, zB, w, l, q, c);
    slab_store(slab, acc, bbB, q, c);
    if (y == 0) {
        store_rows(S, slab, m0, w, l);
    } else {
        __syncthreads();                      // V slab visible
#pragma unroll
        for (int i = 0; i < 16; ++i) {
            int gr = m0 + w * 16 + i;
            ushort4 vr = *(const ushort4*)&cslab[(w * 16 + i) * 68 + koff];
            if (gr < N_NODES) {
                bf16x8 ov;
                ov[0] = (short)kreg[i].x; ov[1] = (short)kreg[i].y;
                ov[2] = (short)kreg[i].z; ov[3] = (short)kreg[i].w;
                ov[4] = (short)vr.x;      ov[5] = (short)vr.y;
                ov[6] = (short)vr.z;      ov[7] = (short)vr.w;
                *(bf16x8*)&KV[(size_t)gr * 512 + l * 8] = ov;
            }
        }
    }
}

// ---------- K2: fused attention + PD GEMM ----------
// 512 threads = 8 waves. Wave w computes attention out-rows w*8..w*8+8 directly
// into the PD A-tile in LDS (pd-swizzled bf16), then the block runs
// PD = out_tile @ [W1_top|W1_bot] and stores PD (aliased onto Q — each block
// touches only its own Q rows, and reads them before writing).
__global__ __launch_bounds__(512, 6) void attn_pd(
    const int* __restrict__ rp, const int* __restrict__ bsum,
    const int* __restrict__ deg, const int* __restrict__ csr_src,
    const unsigned short* __restrict__ Q, const unsigned short* __restrict__ KV,
    const unsigned short* __restrict__ S,
    const unsigned short* __restrict__ Wcp,
    unsigned short* __restrict__ PD)
{
    __shared__ __align__(16) short sh[8 * PSLAB_W];   // 41216 B union:
    short* As = sh;                                    //   As [64][256] swizzled (32 KB)
                                                       //   slab 8 x [64][40] after barrier

    const int t = threadIdx.x;
    const int w = t >> 6, l = t & 63;
    const int q = l >> 4, c = l & 15;
    const int m0 = blockIdx.x * 64;

    // node metadata for this wave's 8 nodes, gathered wave-wide once
    int meta = 0;
    {
        int nn = m0 + w * 8 + (l & 7);
        if (nn < N_NODES) {
            if (l < 8)       meta = rp[nn] + bsum[nn >> 10];
            else if (l < 16) meta = deg[nn];
        }
    }

    // ---- attention phase: wave w -> rows w*8 .. w*8+8 ----
    for (int i = 0; i < 8; ++i) {
        int row  = w * 8 + i;
        int node = m0 + row;
        if (node < N_NODES) {
            int start = __shfl(meta, i);
            int cnt   = __shfl(meta, 8 + i);

            float q0, q1, q2, q3;   // pre-scaled by 1/sqrt(64)
            ushort4 su;
            {
                ushort4 u = *(const ushort4*)&Q[(size_t)node * HD + l * 4];
                su = *(const ushort4*)&S[(size_t)node * HD + l * 4];   // hoisted
                q0 = bf2f(u.x) * 0.125f; q1 = bf2f(u.y) * 0.125f;
                q2 = bf2f(u.z) * 0.125f; q3 = bf2f(u.w) * 0.125f;
            }

            float d = 0.f;
            float a0 = 0.f, a1 = 0.f, a2 = 0.f, a3 = 0.f;

            int i2 = 0;
            for (; i2 + 4 <= cnt; i2 += 4) {
                int s0 = csr_src[start + i2];
                int s1 = csr_src[start + i2 + 1];
                int s2 = csr_src[start + i2 + 2];
                int s3 = csr_src[start + i2 + 3];
                bf16x8 k0 = *(const bf16x8*)&KV[(size_t)s0 * 512 + l * 8];
                bf16x8 k1 = *(const bf16x8*)&KV[(size_t)s1 * 512 + l * 8];
                bf16x8 k2 = *(const bf16x8*)&KV[(size_t)s2 * 512 + l * 8];
                bf16x8 k3 = *(const bf16x8*)&KV[(size_t)s3 * 512 + l * 8];
                float sA = q0 * bf2f((unsigned short)k0[0]) + q1 * bf2f((unsigned short)k0[1])
                         + q2 * bf2f((unsigned short)k0[2]) + q3 * bf2f((unsigned short)k0[3]);
                float sB = q0 * bf2f((unsigned short)k1[0]) + q1 * bf2f((unsigned short)k1[1])
                         + q2 * bf2f((unsigned short)k1[2]) + q3 * bf2f((unsigned short)k1[3]);
                float sC = q0 * bf2f((unsigned short)k2[0]) + q1 * bf2f((unsigned short)k2[1])
                         + q2 * bf2f((unsigned short)k2[2]) + q3 * bf2f((unsigned short)k2[3]);
                float sD = q0 * bf2f((unsigned short)k3[0]) + q1 * bf2f((unsigned short)k3[1])
                         + q2 * bf2f((unsigned short)k3[2]) + q3 * bf2f((unsigned short)k3[3]);
                sA += __shfl_xor(sA, 1); sB += __shfl_xor(sB, 1);
                sC += __shfl_xor(sC, 1); sD += __shfl_xor(sD, 1);
                sA += __shfl_xor(sA, 2); sB += __shfl_xor(sB, 2);
                sC += __shfl_xor(sC, 2); sD += __shfl_xor(sD, 2);
                sA += __shfl_xor(sA, 4); sB += __shfl_xor(sB, 4);
                sC += __shfl_xor(sC, 4); sD += __shfl_xor(sD, 4);
                sA += __shfl_xor(sA, 8); sB += __shfl_xor(sB, 8);
                sC += __shfl_xor(sC, 8); sD += __shfl_xor(sD, 8);
                float eA = __expf(sA), eB = __expf(sB), eC = __expf(sC), eD = __expf(sD);
                d += (eA + eB) + (eC + eD);
                a0 += eA * bf2f((unsigned short)k0[4]) + eB * bf2f((unsigned short)k1[4])
                    + eC * bf2f((unsigned short)k2[4]) + eD * bf2f((unsigned short)k3[4]);
                a1 += eA * bf2f((unsigned short)k0[5]) + eB * bf2f((unsigned short)k1[5])
                    + eC * bf2f((unsigned short)k2[5]) + eD * bf2f((unsigned short)k3[5]);
                a2 += eA * bf2f((unsigned short)k0[6]) + eB * bf2f((unsigned short)k1[6])
                    + eC * bf2f((unsigned short)k2[6]) + eD * bf2f((unsigned short)k3[6]);
                a3 += eA * bf2f((unsigned short)k0[7]) + eB * bf2f((unsigned short)k1[7])
                    + eC * bf2f((unsigned short)k2[7]) + eD * bf2f((unsigned short)k3[7]);
            }
            if (i2 + 2 <= cnt) {
                int s0 = csr_src[start + i2];
                int s1 = csr_src[start + i2 + 1];
                bf16x8 k0 = *(const bf16x8*)&KV[(size_t)s0 * 512 + l * 8];
                bf16x8 k1 = *(const bf16x8*)&KV[(size_t)s1 * 512 + l * 8];
                float sA = q0 * bf2f((unsigned short)k0[0]) + q1 * bf2f((unsigned short)k0[1])
                         + q2 * bf2f((unsigned short)k0[2]) + q3 * bf2f((unsigned short)k0[3]);
                float sB = q0 * bf2f((unsigned short)k1[0]) + q1 * bf2f((unsigned short)k1[1])
                         + q2 * bf2f((unsigned short)k1[2]) + q3 * bf2f((unsigned short)k1[3]);
                sA += __shfl_xor(sA, 1); sB += __shfl_xor(sB, 1);
                sA += __shfl_xor(sA, 2); sB += __shfl_xor(sB, 2);
                sA += __shfl_xor(sA, 4); sB += __shfl_xor(sB, 4);
                sA += __shfl_xor(sA, 8); sB += __shfl_xor(sB, 8);
                float eA = __expf(sA), eB = __expf(sB);
                d += eA + eB;
                a0 += eA * bf2f((unsigned short)k0[4]) + eB * bf2f((unsigned short)k1[4]);
                a1 += eA * bf2f((unsigned short)k0[5]) + eB * bf2f((unsigned short)k1[5]);
                a2 += eA * bf2f((unsigned short)k0[6]) + eB * bf2f((unsigned short)k1[6]);
                a3 += eA * bf2f((unsigned short)k0[7]) + eB * bf2f((unsigned short)k1[7]);
                i2 += 2;
            }
            if (i2 < cnt) {
                int s0 = csr_src[start + i2];
                bf16x8 k0 = *(const bf16x8*)&KV[(size_t)s0 * 512 + l * 8];
                float sA = q0 * bf2f((unsigned short)k0[0]) + q1 * bf2f((unsigned short)k0[1])
                         + q2 * bf2f((unsigned short)k0[2]) + q3 * bf2f((unsigned short)k0[3]);
                sA += __shfl_xor(sA, 1);
                sA += __shfl_xor(sA, 2);
                sA += __shfl_xor(sA, 4);
                sA += __shfl_xor(sA, 8);
                float eA = __expf(sA);
                d += eA;
                a0 += eA * bf2f((unsigned short)k0[4]);
                a1 += eA * bf2f((unsigned short)k0[5]);
                a2 += eA * bf2f((unsigned short)k0[6]);
                a3 += eA * bf2f((unsigned short)k0[7]);
            }

            float inv = 1.f / (d + 1e-16f);
            ushort4 ov = make_ushort4(fbf(bf2f(su.x) + a0 * inv),
                                      fbf(bf2f(su.y) + a1 * inv),
                                      fbf(bf2f(su.z) + a2 * inv),
                                      fbf(bf2f(su.w) + a3 * inv));
            // write into PD A-tile, pd-swizzled: logical 16B-chunk lc=l>>1 of row
            // stored at physical chunk lc^(row&7), half (l&1)
            *(ushort4*)&As[row * 256 + (((l >> 1) ^ (row & 7)) << 3) + ((l & 1) << 2)] = ov;
        }
    }
    __syncthreads();   // out-tile complete

    // ---- PD GEMM phase: 8 waves x 2 N-tiles, K=256 ----
    f32x4 acc[4][2];
#pragma unroll
    for (int mt = 0; mt < 4; ++mt)
#pragma unroll
        for (int nt = 0; nt < 2; ++nt) acc[mt][nt] = (f32x4){0.f, 0.f, 0.f, 0.f};

#pragma unroll
    for (int kt = 0; kt < 8; ++kt) {
        bf16x8 af[4];
#pragma unroll
        for (int mt = 0; mt < 4; ++mt) {
            int row  = mt * 16 + c;
            int slot = (kt * 4 + q) ^ (row & 7);
            af[mt] = *(const bf16x8*)&As[row * 256 + slot * 8];
        }
#pragma unroll
        for (int nt = 0; nt < 2; ++nt) {
            int ntg = w * 2 + nt;
            bf16x8 bv8 = *(const bf16x8*)&Wcp[(size_t)((kt * 16 + ntg) * 64 + l) * 8];
#pragma unroll
            for (int mt = 0; mt < 4; ++mt)
                acc[mt][nt] = __builtin_amdgcn_mfma_f32_16x16x32_bf16(af[mt], bv8, acc[mt][nt], 0, 0, 0);
        }
    }
    __syncthreads();   // all As reads done; slab aliases As

    short* slab = &sh[w * PSLAB_W];   // [64][40], cols w*32..w*32+32
#pragma unroll
    for (int nt = 0; nt < 2; ++nt)
#pragma unroll
        for (int mt = 0; mt < 4; ++mt)
#pragma unroll
            for (int r = 0; r < 4; ++r)
                slab[(mt * 16 + q * 4 + r) * 40 + nt * 16 + c] =
                    (short)fbf(acc[mt][nt][r]);
    __syncthreads();   // slabs visible cross-wave

    // store: wave w stores rows w*8..w*8+8; lane l -> col-chunk cc=l&31 (8 cols)
    const int cc = l & 31;
    const short* sb = &sh[(cc >> 2) * PSLAB_W + (cc & 3) * 8];
#pragma unroll
    for (int i = 0; i < 4; ++i) {
        int row = w * 8 + i * 2 + (l >> 5);
        int gr  = m0 + row;
        if (gr < N_NODES)
            *(bf16x8*)&PD[(size_t)gr * HD + cc * 8] = *(const bf16x8*)&sb[row * 40];
    }
}

// ---------- K5: light edge MLP — h1 = relu(P[src]+D[dst]+b1); layer2 MFMA; layer3 ----------
__global__ __launch_bounds__(256) void edge_mlp_pd(
    const int* __restrict__ csr_src, const int* __restrict__ csr_dst,
    const int* __restrict__ csr_eid,
    const unsigned short* __restrict__ PD,
    const float* __restrict__ b1,
    const unsigned short* __restrict__ W2p, const float* __restrict__ b2,
    const float* __restrict__ W3, const float* __restrict__ b3,
    float* __restrict__ rating)
{
    __shared__ __align__(16) char lds[64 * 136 * 2];   // 17408 B union:
    short* h1t = (short*)lds;                          //   h1 bf16 [64][136]
    float* h2s = (float*)lds;                          //   h2 f32 [64][65] (aliases after barrier)

    const int t = threadIdx.x;
    const int w = t >> 6, l = t & 63;
    const int q = l >> 4, c = l & 15;
    const int e0 = blockIdx.x * 64;

    // stage h1 = relu(P[src] + D[dst] + b1): 64 rows x 128 cols bf16
#pragma unroll
    for (int j = 0; j < 4; ++j) {
        int idx = t + j * 256;          // 1024 chunks of 8 elems
        int row = idx >> 4, ch = idx & 15;
        int src = csr_src[e0 + row];
        int dst = csr_dst[e0 + row];
        bf16x8 pv = *(const bf16x8*)&PD[(size_t)src * HD + ch * 8];
        bf16x8 dv = *(const bf16x8*)&PD[(size_t)dst * HD + 128 + ch * 8];
        float4 ba = *(const float4*)&b1[ch * 8];
        float4 bb = *(const float4*)&b1[ch * 8 + 4];
        bf16x8 hv;
        hv[0] = (short)fbf(fmaxf(bf2f((unsigned short)pv[0]) + bf2f((unsigned short)dv[0]) + ba.x, 0.f));
        hv[1] = (short)fbf(fmaxf(bf2f((unsigned short)pv[1]) + bf2f((unsigned short)dv[1]) + ba.y, 0.f));
        hv[2] = (short)fbf(fmaxf(bf2f((unsigned short)pv[2]) + bf2f((unsigned short)dv[2]) + ba.z, 0.f));
        hv[3] = (short)fbf(fmaxf(bf2f((unsigned short)pv[3]) + bf2f((unsigned short)dv[3]) + ba.w, 0.f));
        hv[4] = (short)fbf(fmaxf(bf2f((unsigned short)pv[4]) + bf2f((unsigned short)dv[4]) + bb.x, 0.f));
        hv[5] = (short)fbf(fmaxf(bf2f((unsigned short)pv[5]) + bf2f((unsigned short)dv[5]) + bb.y, 0.f));
        hv[6] = (short)fbf(fmaxf(bf2f((unsigned short)pv[6]) + bf2f((unsigned short)dv[6]) + bb.z, 0.f));
        hv[7] = (short)fbf(fmaxf(bf2f((unsigned short)pv[7]) + bf2f((unsigned short)dv[7]) + bb.w, 0.f));
        *(bf16x8*)&h1t[row * 136 + ch * 8] = hv;
    }
    __syncthreads();

    // layer2 MFMA: [64,128] @ [128,64]
    f32x4 acc2[4];
#pragma unroll
    for (int i = 0; i < 4; ++i) acc2[i] = (f32x4){0.f, 0.f, 0.f, 0.f};
#pragma unroll
    for (int kt = 0; kt < 4; ++kt) {
        bf16x8 av = *(const bf16x8*)&h1t[(w * 16 + c) * 136 + kt * 32 + q * 8];
#pragma unroll
        for (int nt = 0; nt < 4; ++nt) {
            bf16x8 bv = *(const bf16x8*)&W2p[(size_t)((kt * 4 + nt) * 64 + l) * 8];
            acc2[nt] = __builtin_amdgcn_mfma_f32_16x16x32_bf16(av, bv, acc2[nt], 0, 0, 0);
        }
    }
    __syncthreads();   // h1 reads done; h2 aliases

#pragma unroll
    for (int nt = 0; nt < 4; ++nt) {
        float bv = b2[nt * 16 + c];
#pragma unroll
        for (int r = 0; r < 4; ++r)
            h2s[(w * 16 + q * 4 + r) * 65 + nt * 16 + c] = fmaxf(acc2[nt][r] + bv, 0.f);
    }
    __syncthreads();

    // layer3: all 256 threads — 4 partials per edge + shfl reduce
    {
        int e = t >> 2, part = t & 3;
        float a = 0.f;
#pragma unroll
        for (int kk = 0; kk < 16; ++kk)
            a += h2s[e * 65 + part * 16 + kk] * W3[part * 16 + kk];
        a += __shfl_xor(a, 1);
        a += __shfl_xor(a, 2);
        if (part == 0)
            rating[csr_eid[e0 + e]] = 4.f / (1.f + __expf(-(a + b3[0]))) + 1.f;
    }
}

extern "C" void kernel_launch(void* const* d_in, const int* in_sizes, int n_in,
                              void* d_out, int out_size, void* d_ws, size_t ws_size,
                              hipStream_t stream) {
    const int*   ei  = (const int*)d_in[0];    // [2, E]
    const float* x   = (const float*)d_in[2];
    const float* mem = (const float*)d_in[3];
    const float* Wq  = (const float*)d_in[4];
    const float* bq  = (const float*)d_in[5];
    const float* Wk  = (const float*)d_in[6];
    const float* bk  = (const float*)d_in[7];
    const float* Wv  = (const float*)d_in[8];
    const float* bv  = (const float*)d_in[9];
    const float* Ws  = (const float*)d_in[10];
    const float* bs  = (const float*)d_in[11];
    const float* W1  = (const float*)d_in[12];
    const float* b1  = (const float*)d_in[13];
    const float* W2  = (const float*)d_in[14];
    const float* b2  = (const float*)d_in[15];
    const float* W3  = (const float*)d_in[16];
    const float* b3  = (const float*)d_in[17];
    float* rating = (float*)d_out;

    // Workspace (~237 MB):
    //   Q  [N,256] bf16 (PD aliases Q after attn_pd)          51.2 MB
    //   KV [N,512] bf16 (lane-interleaved K|V)               102.4 MB
    //   S  [N,256] bf16                                       51.2 MB
    //   H  [N,128] bf16 (x+mem)                               25.6 MB
    //   rp, deg, cursor, csr_*, bsum, packs                   ~6.8 MB
    unsigned short* Q = (unsigned short*)d_ws;
    const size_t NHDe = (size_t)N_NODES * HD;   // 25.6M elements
    unsigned short* KV = Q + NHDe;              // N*512 elements
    unsigned short* S  = KV + 2 * NHDe;
    unsigned short* H  = S + NHDe;              // N*128 elements
    int* rp      = (int*)(H + (size_t)N_NODES * HID);
    int* deg     = rp + N_NODES;
    int* cursor  = deg + N_NODES;
    int* csr_src = cursor + N_NODES;
    int* csr_dst = csr_src + N_EDGES;
    int* csr_eid = csr_dst + N_EDGES;
    int* bsum    = csr_eid + N_EDGES;
    unsigned short* Wp  = (unsigned short*)(bsum + 128);
    unsigned short* Wcp = Wp + 16384 * 8;
    unsigned short* W2p = Wcp + 8192 * 8;
    unsigned short* PD  = Q;   // attn_pd writes PD in place of Q (row-owner-only)

    const int eblk  = (N_EDGES + 255) / 256;
    const int pblk  = (N_NODES * HID / 8 + 255) / 256;   // 6250
    const int gblk  = (N_NODES + 63) / 64;               // 1563

    // CSR build + weight packing (deg and cursor are adjacent -> one memset)
    hipMemsetAsync(deg, 0, sizeof(int) * 2 * N_NODES, stream);
    k_deg<<<eblk, 256, 0, stream>>>(ei, deg);
    k_scan1<<<NB_SCAN, 256, 0, stream>>>(deg, rp, bsum);
    k_scan2<<<1, 256, 0, stream>>>(bsum);
    k_bucket<<<eblk, 256, 0, stream>>>(ei, rp, bsum, cursor, csr_src, csr_dst, csr_eid);
    pack_all<<<100, 256, 0, stream>>>(Wq, Wk, Wv, Ws, W1, W2, Wp, Wcp, W2p);

    // H = bf16(x + mem), one streaming pass
    k_pre<<<pblk, 256, 0, stream>>>(x, mem, H);

    // projections: y=0 -> Q,S ; y=1 -> K,V (merged interleaved store)
    gemm4<<<dim3(gblk, 2), dim3(256), 0, stream>>>(
        H, Wp, bq, bk, bv, bs, Q, KV, S);

    // fused attention + PD GEMM (out-tile stays in LDS; PD overwrites Q)
    attn_pd<<<gblk, 512, 0, stream>>>(rp, bsum, deg, csr_src, Q, KV, S, Wcp, PD);

    // light edge MLP in CSR order
    edge_mlp_pd<<<N_EDGES / 64, 256, 0, stream>>>(
        csr_src, csr_dst, csr_eid, PD, b1, W2p, b2, W3, b3, rating);
}